// Round 8
// baseline (273.788 us; speedup 1.0000x reference)
//
#include <hip/hip_runtime.h>
#include <stdint.h>

// ---------------------------------------------------------------------------
// Bucketed linear attention, round 7: GEMM tile 256->128 (same 512 threads,
// 8 waves, wave out 32x64) to get 2 blocks/CU (LDS 64KB, VGPR<=128) so gates
// and fused-epilogue tails overlap across blocks. R3 ledger halved: per
// k-half stage 2 loads, gate vmcnt(2)+barrier. Fused feature-map epilogue
// unchanged (full head per wave).
//   ws layout (~177 MB):
//     xb   bf16 x             33,554,432 B @ 0
//     wq   bf16 qkv_w          6,291,456 B @ 33554432
//     wp   bf16 proj_w         2,097,152 B @ 39845888
//     Qf   bf16 [bkt][n][e]   33,554,432 B @ 41943040
//     Kr   bf16 [bkt][n][d]   33,554,432 B @ 75497472   (exp'd; AT reuses this)
//     Vr   bf16 [bkt][n][e]   33,554,432 B @ 109051904
//     ctxb bf16 [bkt][e][d]   33,554,432 B @ 142606336  (in-place excl scan)
//     ksum f32  [bkt][d]       1,048,576 B @ 176160768  (in-place excl scan)
// ---------------------------------------------------------------------------

typedef unsigned short u16;
typedef unsigned int u32;
typedef u16   u16x4  __attribute__((ext_vector_type(4)));
typedef u16   u16x8  __attribute__((ext_vector_type(8)));
typedef float f32x4  __attribute__((ext_vector_type(4)));
typedef float float4v __attribute__((ext_vector_type(4)));
typedef __bf16 bf16x8 __attribute__((ext_vector_type(8)));

__device__ __forceinline__ u16 f2bf(float f) {
  return __builtin_bit_cast(u16, (__bf16)f);
}
__device__ __forceinline__ float bf2f(u16 h) {
  return (float)__builtin_bit_cast(__bf16, h);
}

__device__ __forceinline__ void stage16(const u16* g, u16* l) {
  __builtin_amdgcn_global_load_lds(
      (const __attribute__((address_space(1))) u32*)g,
      (__attribute__((address_space(3))) u32*)l, 16, 0, 0);
}

// ------------------- fp32 -> bf16 convert (all 3 inputs) --------------------
// ranges (u16x4 units): x 4194304 | qkv_w 786432 | proj_w 262144
__global__ __launch_bounds__(256) void cvt_all(
    const float* __restrict__ x, const float* __restrict__ wqf,
    const float* __restrict__ wpf, u16* __restrict__ xb,
    u16* __restrict__ wq, u16* __restrict__ wp) {
  int i = blockIdx.x * 256 + threadIdx.x;
  const float* in; u16* out; int j;
  if (i < 4194304)      { in = x;   out = xb; j = i; }
  else if (i < 4980736) { in = wqf; out = wq; j = i - 4194304; }
  else                  { in = wpf; out = wp; j = i - 4980736; }
  float4v v = reinterpret_cast<const float4v*>(in)[j];
  u16x4 o;
  o.x = f2bf(v.x); o.y = f2bf(v.y); o.z = f2bf(v.z); o.w = f2bf(v.w);
  reinterpret_cast<u16x4*>(out)[j] = o;
}

// ------------------ 128x128 NT bf16 MFMA GEMM (2 blocks/CU) -----------------
// C[M][N] = A[M][K] @ B[N][K]^T. BK=64, 512 threads = 8 waves (4M x 2N),
// wave out 32x64, 16x16x32 MFMA, acc[2][4]=32 regs. LDS [2 dbuf][2 khalf]
// [128][32] u16 per operand = 64 KB total -> 2 blocks/CU.
// Swizzle: phys 16B slot = logical ^ ((row>>1)&3) on global SOURCE of
// global_load_lds (LDS dest linear) and on ds_read (measured 0 conflicts).
// Gates: vmcnt(2)+barrier per k-half (R3 invariant, counts halved).
// EPI=0: float C + bias (proj). EPI=2: fused feature maps ->
//   bn 0-7: softmax_e(q)*e^-0.5 -> Qf | bn 8-15: exp(k) -> Kr | 16-23: v -> Vr
template <int EPI>
__global__ __launch_bounds__(512, 4) void gemm128(
    const u16* __restrict__ A,      // [M][K] bf16
    const u16* __restrict__ B,      // [N][K] bf16
    const float* __restrict__ bias, // [N] (EPI==0)
    float* __restrict__ Cf,         // (EPI==0)
    u16* __restrict__ Qf, u16* __restrict__ Kr, u16* __restrict__ Vr,
    int N, int K, int NT) {         // NT = K/64
  __shared__ u16 As[2][2][128][32];
  __shared__ u16 Bs[2][2][128][32];
  const int tid = threadIdx.x, lane = tid & 63, wave = tid >> 6;
  const int wm = wave >> 1, wn = wave & 1;
  const int l15 = lane & 15, l4 = lane >> 4;
  const int ntn = N >> 7;
  const int cpx = gridDim.x >> 3;
  const int bid = (blockIdx.x & 7) * cpx + (blockIdx.x >> 3);
  const int bm = bid / ntn, bn = bid % ntn;

  // staging: thread covers 16B at row tid>>2, phys slot tid&3; fetch
  // logical slot (tid&3)^((tid>>3)&3) so LDS dest stays linear.
  const int srow = tid >> 2;
  const int gsl8 = ((tid & 3) ^ ((tid >> 3) & 3)) * 8;
  const u16* Ag = A + (size_t)(bm * 128 + srow) * K + gsl8;
  const u16* Bg = B + (size_t)(bn * 128 + srow) * K + gsl8;

  // ds_read: physical slot = l4 ^ ((row>>1)&3); row = base16 + l15.
  const int slotr = (l4 ^ ((l15 >> 1) & 3)) * 8;

  f32x4 acc[2][4] = {};
  bf16x8 a0, a1, b0, b1, b2, b3;

#define STG(P, buf, kh, kt) \
  stage16(P##g + (kt) + (kh) * 32, &P##s[buf][kh][wave * 16][0]);

#define LDA(kk)                                                    \
  { const u16* p_ = &As[cur][kk][wm * 32 + l15][0] + slotr;        \
    a0 = *(const bf16x8*)(p_);                                     \
    a1 = *(const bf16x8*)(p_ + 512); }

#define LDB(kk)                                                    \
  { const u16* p_ = &Bs[cur][kk][wn * 64 + l15][0] + slotr;        \
    b0 = *(const bf16x8*)(p_);                                     \
    b1 = *(const bf16x8*)(p_ + 512);                               \
    b2 = *(const bf16x8*)(p_ + 1024);                              \
    b3 = *(const bf16x8*)(p_ + 1536); }

#define MM(x, y, z) z = __builtin_amdgcn_mfma_f32_16x16x32_bf16(x, y, z, 0, 0, 0)
#define M4(x, mi)                                                  \
  __builtin_amdgcn_s_setprio(1);                                   \
  MM(x, b0, acc[mi][0]); MM(x, b1, acc[mi][1]);                    \
  MM(x, b2, acc[mi][2]); MM(x, b3, acc[mi][3]);                    \
  __builtin_amdgcn_s_setprio(0);

#define BARF()                                                     \
  { asm volatile("" ::: "memory");                                 \
    __builtin_amdgcn_s_barrier();                                  \
    asm volatile("" ::: "memory"); }

  // prologue: stage tile 0 (4 loads); k0 pair landed, k1 pair in flight.
  STG(A, 0, 0, 0) STG(B, 0, 0, 0) STG(A, 0, 1, 0) STG(B, 0, 1, 0)
  asm volatile("s_waitcnt vmcnt(2)" ::: "memory");
  __builtin_amdgcn_s_barrier();
  asm volatile("" ::: "memory");

  for (int t = 0; t < NT; ++t) {
    const int cur = t & 1, nxt = cur ^ 1;
    const int ktn = (t + 1) << 6;
    const bool pre = (t + 1 < NT);
    // ---- k-half 0 ----
    LDB(0) LDA(0)
    if (pre) STG(A, nxt, 0, ktn)
    M4(a0, 0)
    if (pre) STG(B, nxt, 0, ktn)
    M4(a1, 1)
    // gate: k1(t) pair (oldest 2 outstanding) landed -> k1 readable
    if (pre) { asm volatile("s_waitcnt vmcnt(2)" ::: "memory"); }
    else     { asm volatile("s_waitcnt vmcnt(0)" ::: "memory"); }
    BARF()
    // ---- k-half 1 ----
    LDB(1) LDA(1)
    if (pre) STG(A, nxt, 1, ktn)
    M4(a0, 0)
    if (pre) STG(B, nxt, 1, ktn)
    M4(a1, 1)
    // gate: k0(t+1) pair landed -> next tile k0 readable
    if (pre) { asm volatile("s_waitcnt vmcnt(2)" ::: "memory"); }
    BARF()
  }
#undef STG
#undef LDA
#undef LDB
#undef MM
#undef M4
#undef BARF

  // epilogue: D row=(lane>>4)*4+reg, col=lane&15
  const int row0 = bm * 128 + wm * 32 + l4 * 4;
  const int col0 = bn * 128 + wn * 64 + l15;
  if constexpr (EPI == 0) {
    float bv[4];
#pragma unroll
    for (int ni = 0; ni < 4; ++ni) bv[ni] = bias[col0 + ni * 16];
#pragma unroll
    for (int mi = 0; mi < 2; ++mi)
#pragma unroll
      for (int i = 0; i < 4; ++i) {
        size_t r = (size_t)(row0 + mi * 16 + i) * N;
#pragma unroll
        for (int ni = 0; ni < 4; ++ni)
          Cf[r + col0 + ni * 16] = acc[mi][ni][i] + bv[ni];
      }
  } else {
    // fused feature maps. region & head are block/wave-uniform.
    const int i3 = bn >> 3;                  // 0=q, 1=k, 2=v
    const int h  = ((bn & 7) << 1) + wn;     // global head 0..15
    u16* dst = (i3 == 0) ? Qf : (i3 == 1 ? Kr : Vr);
#pragma unroll
    for (int mi = 0; mi < 2; ++mi)
#pragma unroll
      for (int i = 0; i < 4; ++i) {
        const int row = row0 + mi * 16 + i;
        const int bb = row >> 12, uu = (row >> 6) & 63, nn = row & 63;
        u16* op = dst + ((size_t)((bb * 16 + h) * 64 + uu)) * 4096
                      + nn * 64 + l15;
        float v0 = acc[mi][0][i], v1 = acc[mi][1][i];
        float v2 = acc[mi][2][i], v3 = acc[mi][3][i];
        if (i3 == 0) {
          // row softmax over e=64: 4 in-lane + 16-lane group (masks 1,2,4,8
          // toggle l15 bits only; l4 row-subgroup untouched)
          float mx = fmaxf(fmaxf(v0, v1), fmaxf(v2, v3));
          mx = fmaxf(mx, __shfl_xor(mx, 1));
          mx = fmaxf(mx, __shfl_xor(mx, 2));
          mx = fmaxf(mx, __shfl_xor(mx, 4));
          mx = fmaxf(mx, __shfl_xor(mx, 8));
          float e0 = __expf(v0 - mx), e1 = __expf(v1 - mx);
          float e2 = __expf(v2 - mx), e3 = __expf(v3 - mx);
          float s = e0 + e1 + e2 + e3;
          s += __shfl_xor(s, 1); s += __shfl_xor(s, 2);
          s += __shfl_xor(s, 4); s += __shfl_xor(s, 8);
          float inv = 0.125f / s;  // e^-0.5 = 1/8
          op[0]  = f2bf(e0 * inv); op[16] = f2bf(e1 * inv);
          op[32] = f2bf(e2 * inv); op[48] = f2bf(e3 * inv);
        } else if (i3 == 1) {
          op[0]  = f2bf(__expf(v0)); op[16] = f2bf(__expf(v1));
          op[32] = f2bf(__expf(v2)); op[48] = f2bf(__expf(v3));
        } else {
          op[0]  = f2bf(v0); op[16] = f2bf(v1);
          op[32] = f2bf(v2); op[48] = f2bf(v3);
        }
      }
  }
}

// ---------------- per-bucket K^T V + ksum (from Kr, Vr) ---------------------
// One block per bucket. Kr already exp'd. LDS-transpose then 16x16x32 MFMA.
__global__ __launch_bounds__(256) void buildctx(
    const u16* __restrict__ Kr,  // [bkt][n][d] bf16 (exp'd)
    const u16* __restrict__ Vr,  // [bkt][n][e] bf16
    u16* __restrict__ ctxb, float* __restrict__ ksum) {
  const int bid = blockIdx.x;
  const int tid = threadIdx.x, lane = tid & 63, wave = tid >> 6;
  const int l15 = lane & 15, l4 = lane >> 4;
  __shared__ float ts[64][65];
  __shared__ u16 KtL[64][72];
  __shared__ u16 VtL[64][72];
  __shared__ float dp[64][4];

  const size_t base = (size_t)bid * 4096;

  // K stage + transpose into KtL
  {
    int n = tid >> 2, c = tid & 3;
    const u16* kp = Kr + base + n * 64 + c * 16;
#pragma unroll
    for (int j = 0; j < 16; ++j) ts[n][c * 16 + j] = bf2f(kp[j]);
  }
  __syncthreads();
  {
    int d = tid >> 2, c = tid & 3;
    u16x8 o0, o1;
#pragma unroll
    for (int j = 0; j < 8; ++j) o0[j] = f2bf(ts[c * 16 + j][d]);
#pragma unroll
    for (int j = 0; j < 8; ++j) o1[j] = f2bf(ts[c * 16 + 8 + j][d]);
    *reinterpret_cast<u16x8*>(&KtL[d][c * 16])     = o0;
    *reinterpret_cast<u16x8*>(&KtL[d][c * 16 + 8]) = o1;
  }
  __syncthreads();
  // ksum partials; V stage into ts
  {
    int d = tid & 63, q = tid >> 6;
    float a = 0.f;
#pragma unroll
    for (int j = 0; j < 16; ++j) a += bf2f(KtL[d][q * 16 + j]);
    dp[d][q] = a;
  }
  {
    int n = tid >> 2, c = tid & 3;
    const u16* vp = Vr + base + n * 64 + c * 16;
#pragma unroll
    for (int j = 0; j < 16; ++j) ts[n][c * 16 + j] = bf2f(vp[j]);
  }
  __syncthreads();
  if (tid < 64)
    ksum[(size_t)bid * 64 + tid] = dp[tid][0] + dp[tid][1] + dp[tid][2] + dp[tid][3];
  {
    int e = tid >> 2, c = tid & 3;
    u16x8 o0, o1;
#pragma unroll
    for (int j = 0; j < 8; ++j) o0[j] = f2bf(ts[c * 16 + j][e]);
#pragma unroll
    for (int j = 0; j < 8; ++j) o1[j] = f2bf(ts[c * 16 + 8 + j][e]);
    *reinterpret_cast<u16x8*>(&VtL[e][c * 16])     = o0;
    *reinterpret_cast<u16x8*>(&VtL[e][c * 16 + 8]) = o1;
  }
  __syncthreads();

  // ctxT[e][d] = sum_n VtL[e][n] * KtL[d][n]; wave -> 16 e-rows
  f32x4 acc[4] = {};
#pragma unroll
  for (int kk = 0; kk < 2; ++kk) {
    bf16x8 av = *reinterpret_cast<const bf16x8*>(&VtL[wave * 16 + l15][kk * 32 + l4 * 8]);
#pragma unroll
    for (int ni = 0; ni < 4; ++ni) {
      bf16x8 bk = *reinterpret_cast<const bf16x8*>(&KtL[ni * 16 + l15][kk * 32 + l4 * 8]);
      acc[ni] = __builtin_amdgcn_mfma_f32_16x16x32_bf16(av, bk, acc[ni], 0, 0, 0);
    }
  }
  u16* cb = ctxb + base;
#pragma unroll
  for (int ni = 0; ni < 4; ++ni)
#pragma unroll
    for (int i = 0; i < 4; ++i)
      cb[(wave * 16 + l4 * 4 + i) * 64 + ni * 16 + l15] = f2bf(acc[ni][i]);
}

// -------------------- in-place exclusive cumsum over u ----------------------
__global__ __launch_bounds__(256) void scanctx(
    u16* __restrict__ ctxb, float* __restrict__ ksum) {
  const int bh = blockIdx.x >> 2, c = blockIdx.x & 3;
  const int tid = threadIdx.x;
  u16* p = ctxb + (size_t)bh * 64 * 4096 + c * 1024 + tid * 4;
  float* kp = ksum + (size_t)bh * 64 * 64 + tid;
  const bool dok = (c == 0) && (tid < 64);

  float r0 = 0.f, r1 = 0.f, r2 = 0.f, r3 = 0.f, runk = 0.f;
#define LC(i) (*reinterpret_cast<const u16x4*>(p + (size_t)(i) * 4096))
#define LK(i) (dok ? kp[(size_t)(i) * 64] : 0.f)
  u16x4 c0 = LC(0), c1 = LC(1), c2 = LC(2), c3 = LC(3);
  float k0 = LK(0), k1 = LK(1), k2 = LK(2), k3 = LK(3);
  for (int u = 0; u < 64; u += 4) {
    const int i4 = u + 4 < 64 ? u + 4 : 63, i5 = u + 5 < 64 ? u + 5 : 63;
    const int i6 = u + 6 < 64 ? u + 6 : 63, i7 = u + 7 < 64 ? u + 7 : 63;
    u16x4 n0 = LC(i4), n1 = LC(i5), n2 = LC(i6), n3 = LC(i7);
    float m0 = LK(i4), m1 = LK(i5), m2 = LK(i6), m3 = LK(i7);
#define STEP(idx, cv, kv)                                                  \
    {                                                                      \
      u16x4 o;                                                             \
      o.x = f2bf(r0); o.y = f2bf(r1); o.z = f2bf(r2); o.w = f2bf(r3);      \
      *reinterpret_cast<u16x4*>(p + (size_t)(idx) * 4096) = o;             \
      if (dok) kp[(size_t)(idx) * 64] = runk;                              \
      r0 += bf2f(cv.x); r1 += bf2f(cv.y); r2 += bf2f(cv.z);                \
      r3 += bf2f(cv.w); runk += kv;                                        \
    }
    STEP(u, c0, k0) STEP(u + 1, c1, k1) STEP(u + 2, c2, k2) STEP(u + 3, c3, k3)
#undef STEP
    c0 = n0; c1 = n1; c2 = n2; c3 = n3;
    k0 = m0; k1 = m1; k2 = m2; k3 = m3;
  }
#undef LC
#undef LK
}

// ---------------- apply: attn = (q @ ctx_excl) * Dinv -> AT -----------------
__global__ __launch_bounds__(256) void apply(
    const u16* __restrict__ Q, const u16* __restrict__ ctxc,
    const float* __restrict__ kcum, u16* __restrict__ AT) {
  const int bid = blockIdx.x;
  const int u = bid & 63, bh = bid >> 6, b = bh >> 4, h = bh & 15;
  const int tid = threadIdx.x, lane = tid & 63, wave = tid >> 6;
  const int l15 = lane & 15, l4 = lane >> 4;
  __shared__ float kc[64];
  __shared__ float dp[64][4];
  __shared__ float dinv[64];

  const size_t base = (size_t)bid * 4096;
  const u16* Qu = Q + base;
  if (tid < 64) kc[tid] = kcum[(size_t)bid * 64 + tid];
  __syncthreads();
  {
    int n = tid & 63, q = tid >> 6;
    const u16* qp = Qu + n * 64 + q * 16;
    float a = 0.f;
#pragma unroll
    for (int j = 0; j < 16; ++j) a += bf2f(qp[j]) * kc[q * 16 + j];
    dp[n][q] = a;
  }
  __syncthreads();
  if (tid < 64)
    dinv[tid] = 1.f / fmaxf(dp[tid][0] + dp[tid][1] + dp[tid][2] + dp[tid][3], 1e-3f);
  __syncthreads();

  f32x4 acc[4] = {};
  const u16* Cu = ctxc + base;
#pragma unroll
  for (int kk = 0; kk < 2; ++kk) {
    bf16x8 aq = *reinterpret_cast<const bf16x8*>(Qu + (wave * 16 + l15) * 64 + kk * 32 + l4 * 8);
#pragma unroll
    for (int ni = 0; ni < 4; ++ni) {
      bf16x8 bc = *reinterpret_cast<const bf16x8*>(Cu + (ni * 16 + l15) * 64 + kk * 32 + l4 * 8);
      acc[ni] = __builtin_amdgcn_mfma_f32_16x16x32_bf16(aq, bc, acc[ni], 0, 0, 0);
    }
  }
  const size_t orow = ((size_t)b * 4096 + u * 64 + wave * 16 + l4 * 4) * 1024 + h * 64;
#pragma unroll
  for (int i = 0; i < 4; ++i) {
    float di = dinv[wave * 16 + l4 * 4 + i];
#pragma unroll
    for (int ni = 0; ni < 4; ++ni)
      AT[orow + (size_t)i * 1024 + ni * 16 + l15] = f2bf(acc[ni][i] * di);
  }
}

// ----------------------------------------------------------------------------
extern "C" void kernel_launch(void* const* d_in, const int* in_sizes, int n_in,
                              void* d_out, int out_size, void* d_ws, size_t ws_size,
                              hipStream_t stream) {
  (void)in_sizes; (void)n_in; (void)out_size; (void)ws_size;
  const float* x      = (const float*)d_in[0];
  const float* qkv_w  = (const float*)d_in[1];
  const float* proj_w = (const float*)d_in[2];
  const float* proj_b = (const float*)d_in[3];
  float* out = (float*)d_out;

  char* ws = (char*)d_ws;
  u16* xb    = (u16*)(ws);
  u16* wq    = (u16*)(ws + 33554432);
  u16* wp    = (u16*)(ws + 39845888);
  u16* Qf    = (u16*)(ws + 41943040);
  u16* Kr    = (u16*)(ws + 75497472);
  u16* Vr    = (u16*)(ws + 109051904);
  u16* ctxb  = (u16*)(ws + 142606336);
  float* ksum = (float*)(ws + 176160768);
  u16* AT    = Kr;  // Kr is dead after buildctx; apply writes AT over it

  cvt_all<<<dim3(20480), dim3(256), 0, stream>>>(x, qkv_w, proj_w, xb, wq, wp);

  gemm128<2><<<dim3(128 * 24), dim3(512), 0, stream>>>(
      xb, wq, nullptr, nullptr, Qf, Kr, Vr, 3072, 1024, 16);
  buildctx<<<dim3(4096), dim3(256), 0, stream>>>(Kr, Vr, ctxb, ksum);
  scanctx<<<dim3(256), dim3(256), 0, stream>>>(ctxb, ksum);
  apply<<<dim3(4096), dim3(256), 0, stream>>>(Qf, ctxb, ksum, AT);
  gemm128<0><<<dim3(128 * 8), dim3(512), 0, stream>>>(
      AT, wp, proj_b, out, nullptr, nullptr, nullptr, 1024, 1024, 16);
}

// Round 9
// 249.114 us; speedup vs baseline: 1.0990x; 1.0990x over previous
//
#include <hip/hip_runtime.h>
#include <stdint.h>

// ---------------------------------------------------------------------------
// Bucketed linear attention, round 8: R6 core (best: 244.9us) +
//   - K/V fused-epilogue outputs stored TRANSPOSED (Kt/Vt[bkt][d|e][n]) via
//     u16x4 stores (4x fewer store insts in the epilogue tail)
//   - buildctx v2: no LDS transposes -- MFMA frags read straight from
//     global Kt/Vt (k=n contiguous), ksum = row sums.
//   ws layout (~177 MB):
//     xb   bf16 x             33,554,432 B @ 0
//     wq   bf16 qkv_w          6,291,456 B @ 33554432
//     wp   bf16 proj_w         2,097,152 B @ 39845888
//     Qf   bf16 [bkt][n][e]   33,554,432 B @ 41943040
//     Kt   bf16 [bkt][d][n]   33,554,432 B @ 75497472   (exp'd; AT reuses)
//     Vt   bf16 [bkt][e][n]   33,554,432 B @ 109051904
//     ctxb bf16 [bkt][e][d]   33,554,432 B @ 142606336  (in-place excl scan)
//     ksum f32  [bkt][d]       1,048,576 B @ 176160768  (in-place excl scan)
// ---------------------------------------------------------------------------

typedef unsigned short u16;
typedef unsigned int u32;
typedef u16   u16x4  __attribute__((ext_vector_type(4)));
typedef u16   u16x8  __attribute__((ext_vector_type(8)));
typedef float f32x4  __attribute__((ext_vector_type(4)));
typedef float float4v __attribute__((ext_vector_type(4)));
typedef __bf16 bf16x8 __attribute__((ext_vector_type(8)));

__device__ __forceinline__ u16 f2bf(float f) {
  return __builtin_bit_cast(u16, (__bf16)f);
}
__device__ __forceinline__ float bf2f(u16 h) {
  return (float)__builtin_bit_cast(__bf16, h);
}

__device__ __forceinline__ void stage16(const u16* g, u16* l) {
  __builtin_amdgcn_global_load_lds(
      (const __attribute__((address_space(1))) u32*)g,
      (__attribute__((address_space(3))) u32*)l, 16, 0, 0);
}

// ------------------- fp32 -> bf16 convert (all 3 inputs) --------------------
// ranges (u16x4 units): x 4194304 | qkv_w 786432 | proj_w 262144
__global__ __launch_bounds__(256) void cvt_all(
    const float* __restrict__ x, const float* __restrict__ wqf,
    const float* __restrict__ wpf, u16* __restrict__ xb,
    u16* __restrict__ wq, u16* __restrict__ wp) {
  int i = blockIdx.x * 256 + threadIdx.x;
  const float* in; u16* out; int j;
  if (i < 4194304)      { in = x;   out = xb; j = i; }
  else if (i < 4980736) { in = wqf; out = wq; j = i - 4194304; }
  else                  { in = wpf; out = wp; j = i - 4980736; }
  float4v v = reinterpret_cast<const float4v*>(in)[j];
  u16x4 o;
  o.x = f2bf(v.x); o.y = f2bf(v.y); o.z = f2bf(v.z); o.w = f2bf(v.w);
  reinterpret_cast<u16x4*>(out)[j] = o;
}

// ------------------ 256x256 NT bf16 MFMA GEMM (R3 schedule) -----------------
// C[M][N] = A[M][K] @ B[N][K]^T. BK=64, 8 waves (2Mx4N), wave out 128x64,
// 16x16x32 MFMA. LDS [2 dbuf][2 khalf][256][32] u16 per operand.
// Swizzle: phys 16B slot = logical ^ ((row>>1)&3) on global SOURCE of
// global_load_lds (LDS dest linear) and on ds_read (measured 0 conflicts).
// Per k-half: 12 ds_reads up front; STG interleaved; vmcnt(4)+barrier gate.
// EPI=0: float C + bias (proj). EPI=2: fused feature maps ->
//   bn 0-3: softmax_e(q)*e^-0.5 -> Qf[bkt][n][e]
//   bn 4-7: exp(k)   -> Kt[bkt][d][n]  (transposed, u16x4 stores)
//   bn 8-11: v       -> Vt[bkt][e][n]  (transposed, u16x4 stores)
template <int EPI>
__global__ __launch_bounds__(512, 2) void gemm256(
    const u16* __restrict__ A,      // [M][K] bf16
    const u16* __restrict__ B,      // [N][K] bf16
    const float* __restrict__ bias, // [N] (EPI==0)
    float* __restrict__ Cf,         // (EPI==0)
    u16* __restrict__ Qf, u16* __restrict__ Kt, u16* __restrict__ Vt,
    int N, int K, int NT) {         // NT = K/64
  __shared__ u16 As[2][2][256][32];
  __shared__ u16 Bs[2][2][256][32];
  const int tid = threadIdx.x, lane = tid & 63, wave = tid >> 6;
  const int wm = wave >> 2, wn = wave & 3;
  const int l15 = lane & 15, l4 = lane >> 4;
  const int ntn = N >> 8;
  const int cpx = gridDim.x >> 3;
  const int bid = (blockIdx.x & 7) * cpx + (blockIdx.x >> 3);
  const int bm = bid / ntn, bn = bid % ntn;

  // staging: thread covers 16B at row (j*128 + tid>>2), phys slot tid&3;
  // fetch logical slot (tid&3)^((tid>>3)&3) so LDS dest stays linear.
  const int srow = tid >> 2;
  const int gsl8 = ((tid & 3) ^ ((tid >> 3) & 3)) * 8;
  const u16* Ag = A + (size_t)(bm * 256 + srow) * K + gsl8;
  const u16* Bg = B + (size_t)(bn * 256 + srow) * K + gsl8;
  const size_t rj = (size_t)128 * K;

  // ds_read: physical slot = l4 ^ ((row>>1)&3); row = base16 + l15.
  const int slotr = (l4 ^ ((l15 >> 1) & 3)) * 8;

  f32x4 acc[8][4] = {};
  bf16x8 a0, a1, a2, a3, a4, a5, a6, a7, b0, b1, b2, b3;

#define STG(P, buf, kh, kt)                                        \
  { const u16* g_ = P##g + (kt) + (kh) * 32;                       \
    stage16(g_,      &P##s[buf][kh][wave * 16][0]);                \
    stage16(g_ + rj, &P##s[buf][kh][128 + wave * 16][0]); }

#define LDA(r0_, r1_, r2_, r3_, kk, mh)                                  \
  { const u16* p_ = &As[cur][kk][wm * 128 + (mh) * 64 + l15][0] + slotr; \
    r0_ = *(const bf16x8*)(p_);                                          \
    r1_ = *(const bf16x8*)(p_ + 512);                                    \
    r2_ = *(const bf16x8*)(p_ + 1024);                                   \
    r3_ = *(const bf16x8*)(p_ + 1536); }

#define LDB(kk)                                                    \
  { const u16* p_ = &Bs[cur][kk][wn * 64 + l15][0] + slotr;        \
    b0 = *(const bf16x8*)(p_);                                     \
    b1 = *(const bf16x8*)(p_ + 512);                               \
    b2 = *(const bf16x8*)(p_ + 1024);                              \
    b3 = *(const bf16x8*)(p_ + 1536); }

#define MM(x, y, z) z = __builtin_amdgcn_mfma_f32_16x16x32_bf16(x, y, z, 0, 0, 0)
#define MFMA16(mb, x0, x1, x2, x3)                                 \
  __builtin_amdgcn_s_setprio(1);                                   \
  MM(x0, b0, acc[(mb) + 0][0]); MM(x0, b1, acc[(mb) + 0][1]);      \
  MM(x0, b2, acc[(mb) + 0][2]); MM(x0, b3, acc[(mb) + 0][3]);      \
  MM(x1, b0, acc[(mb) + 1][0]); MM(x1, b1, acc[(mb) + 1][1]);      \
  MM(x1, b2, acc[(mb) + 1][2]); MM(x1, b3, acc[(mb) + 1][3]);      \
  MM(x2, b0, acc[(mb) + 2][0]); MM(x2, b1, acc[(mb) + 2][1]);      \
  MM(x2, b2, acc[(mb) + 2][2]); MM(x2, b3, acc[(mb) + 2][3]);      \
  MM(x3, b0, acc[(mb) + 3][0]); MM(x3, b1, acc[(mb) + 3][1]);      \
  MM(x3, b2, acc[(mb) + 3][2]); MM(x3, b3, acc[(mb) + 3][3]);      \
  __builtin_amdgcn_s_setprio(0);

#define BARF()                                                     \
  { asm volatile("" ::: "memory");                                 \
    __builtin_amdgcn_s_barrier();                                  \
    asm volatile("" ::: "memory"); }

  // prologue: stage tile 0 fully into buf 0, drain, barrier.
  STG(A, 0, 0, 0) STG(B, 0, 0, 0) STG(A, 0, 1, 0) STG(B, 0, 1, 0)
  asm volatile("s_waitcnt vmcnt(0)" ::: "memory");
  __builtin_amdgcn_s_barrier();
  asm volatile("" ::: "memory");

  for (int t = 0; t < NT; ++t) {
    const int cur = t & 1, nxt = cur ^ 1;
    const int ktn = (t + 1) << 6;
    const bool pre = (t + 1 < NT);
    // ---- k-half 0: 12 ds_reads up front; second MFMA16 stall-free ----
    LDB(0)
    LDA(a0, a1, a2, a3, 0, 0)
    LDA(a4, a5, a6, a7, 0, 1)
    if (pre) STG(A, nxt, 0, ktn)
    MFMA16(0, a0, a1, a2, a3)
    if (pre) STG(B, nxt, 0, ktn)
    MFMA16(4, a4, a5, a6, a7)
    // gate: all waves' k1 staging (prev iter) landed -> k1 readable
    if (pre) { asm volatile("s_waitcnt vmcnt(4)" ::: "memory"); }
    else     { asm volatile("s_waitcnt vmcnt(0)" ::: "memory"); }
    BARF()
    // ---- k-half 1 ----
    LDB(1)
    LDA(a0, a1, a2, a3, 1, 0)
    LDA(a4, a5, a6, a7, 1, 1)
    if (pre) STG(A, nxt, 1, ktn)
    MFMA16(0, a0, a1, a2, a3)
    if (pre) STG(B, nxt, 1, ktn)
    MFMA16(4, a4, a5, a6, a7)
    // gate: all waves' k0 staging (this iter) landed -> next tile k0 ok
    if (pre) { asm volatile("s_waitcnt vmcnt(4)" ::: "memory"); }
    BARF()
  }
#undef STG
#undef LDA
#undef LDB
#undef MM
#undef MFMA16
#undef BARF

  // epilogue: D row=(lane>>4)*4+reg, col=lane&15
  const int row0 = bm * 256 + wm * 128 + l4 * 4;
  const int col0 = bn * 256 + wn * 64 + l15;
  if constexpr (EPI == 0) {
    float bv[4];
#pragma unroll
    for (int ni = 0; ni < 4; ++ni) bv[ni] = bias[col0 + ni * 16];
#pragma unroll
    for (int mi = 0; mi < 8; ++mi)
#pragma unroll
      for (int i = 0; i < 4; ++i) {
        size_t r = (size_t)(row0 + mi * 16 + i) * N;
#pragma unroll
        for (int ni = 0; ni < 4; ++ni)
          Cf[r + col0 + ni * 16] = acc[mi][ni][i] + bv[ni];
      }
  } else {
    // fused feature maps. region & head are block/wave-uniform.
    const int i3 = bn >> 2;                  // 0=q, 1=k, 2=v
    const int h  = ((bn & 3) << 2) + wn;     // global head 0..15
    if (i3 == 0) {
#pragma unroll
      for (int mi = 0; mi < 8; ++mi)
#pragma unroll
        for (int i = 0; i < 4; ++i) {
          const int row = row0 + mi * 16 + i;
          const int bb = row >> 12, uu = (row >> 6) & 63, nn = row & 63;
          u16* op = Qf + ((size_t)((bb * 16 + h) * 64 + uu)) * 4096
                        + nn * 64 + l15;
          float v0 = acc[mi][0][i], v1 = acc[mi][1][i];
          float v2 = acc[mi][2][i], v3 = acc[mi][3][i];
          // row softmax over e=64: 4 in-lane + 16-lane group (masks 1,2,4,8
          // toggle l15 bits only; l4 row-subgroup untouched)
          float mx = fmaxf(fmaxf(v0, v1), fmaxf(v2, v3));
          mx = fmaxf(mx, __shfl_xor(mx, 1));
          mx = fmaxf(mx, __shfl_xor(mx, 2));
          mx = fmaxf(mx, __shfl_xor(mx, 4));
          mx = fmaxf(mx, __shfl_xor(mx, 8));
          float e0 = __expf(v0 - mx), e1 = __expf(v1 - mx);
          float e2 = __expf(v2 - mx), e3 = __expf(v3 - mx);
          float s = e0 + e1 + e2 + e3;
          s += __shfl_xor(s, 1); s += __shfl_xor(s, 2);
          s += __shfl_xor(s, 4); s += __shfl_xor(s, 8);
          float inv = 0.125f / s;  // e^-0.5 = 1/8
          op[0]  = f2bf(e0 * inv); op[16] = f2bf(e1 * inv);
          op[32] = f2bf(e2 * inv); op[48] = f2bf(e3 * inv);
        }
    } else {
      // K/V: transposed [bkt][d|e][n] -- reg idx i spans 4 consecutive n,
      // so each (mi,ni) is one u16x4 store.
      u16* dst = (i3 == 1) ? Kt : Vt;
#pragma unroll
      for (int mi = 0; mi < 8; ++mi) {
        const int row = row0 + mi * 16;  // rows row..row+3 (same bucket)
        const int bb = row >> 12, uu = (row >> 6) & 63, nn = row & 63;
        u16* op = dst + ((size_t)((bb * 16 + h) * 64 + uu)) * 4096 + nn;
#pragma unroll
        for (int ni = 0; ni < 4; ++ni) {
          const int d = ni * 16 + l15;
          u16x4 o;
          if (i3 == 1) {
            o.x = f2bf(__expf(acc[mi][ni][0]));
            o.y = f2bf(__expf(acc[mi][ni][1]));
            o.z = f2bf(__expf(acc[mi][ni][2]));
            o.w = f2bf(__expf(acc[mi][ni][3]));
          } else {
            o.x = f2bf(acc[mi][ni][0]); o.y = f2bf(acc[mi][ni][1]);
            o.z = f2bf(acc[mi][ni][2]); o.w = f2bf(acc[mi][ni][3]);
          }
          *reinterpret_cast<u16x4*>(op + d * 64) = o;
        }
      }
    }
  }
}

// ---------------- per-bucket K^T V + ksum (from Kt, Vt) ---------------------
// One block per bucket. Kt/Vt already transposed ([d|e][n], n contiguous):
// MFMA frags read straight from global; ksum = row sums. No LDS staging.
__global__ __launch_bounds__(256) void buildctx(
    const u16* __restrict__ Kt,  // [bkt][d][n] bf16 (exp'd)
    const u16* __restrict__ Vt,  // [bkt][e][n] bf16
    u16* __restrict__ ctxb, float* __restrict__ ksum) {
  const int bid = blockIdx.x;
  const int tid = threadIdx.x, lane = tid & 63, wave = tid >> 6;
  const int l15 = lane & 15, l4 = lane >> 4;
  __shared__ float dp[64][4];
  const size_t base = (size_t)bid * 4096;

  // ksum partials: dp[d][c] = sum Kt[d][c*16 .. c*16+16)
  {
    int d = tid >> 2, c = tid & 3;
    const u16* kp = Kt + base + d * 64 + c * 16;
    float a = 0.f;
#pragma unroll
    for (int j = 0; j < 16; ++j) a += bf2f(kp[j]);
    dp[d][c] = a;
  }

  // ctxT[e][d] = sum_n Vt[e][n] * Kt[d][n]; wave -> 16 e-rows
  f32x4 acc[4] = {};
#pragma unroll
  for (int kk = 0; kk < 2; ++kk) {
    bf16x8 av = *reinterpret_cast<const bf16x8*>(
        Vt + base + (wave * 16 + l15) * 64 + kk * 32 + l4 * 8);
#pragma unroll
    for (int ni = 0; ni < 4; ++ni) {
      bf16x8 bk = *reinterpret_cast<const bf16x8*>(
          Kt + base + (ni * 16 + l15) * 64 + kk * 32 + l4 * 8);
      acc[ni] = __builtin_amdgcn_mfma_f32_16x16x32_bf16(av, bk, acc[ni], 0, 0, 0);
    }
  }
  __syncthreads();
  if (tid < 64)
    ksum[(size_t)bid * 64 + tid] = dp[tid][0] + dp[tid][1] + dp[tid][2] + dp[tid][3];
  u16* cb = ctxb + base;
#pragma unroll
  for (int ni = 0; ni < 4; ++ni)
#pragma unroll
    for (int i = 0; i < 4; ++i)
      cb[(wave * 16 + l4 * 4 + i) * 64 + ni * 16 + l15] = f2bf(acc[ni][i]);
}

// -------------------- in-place exclusive cumsum over u ----------------------
__global__ __launch_bounds__(256) void scanctx(
    u16* __restrict__ ctxb, float* __restrict__ ksum) {
  const int bh = blockIdx.x >> 2, c = blockIdx.x & 3;
  const int tid = threadIdx.x;
  u16* p = ctxb + (size_t)bh * 64 * 4096 + c * 1024 + tid * 4;
  float* kp = ksum + (size_t)bh * 64 * 64 + tid;
  const bool dok = (c == 0) && (tid < 64);

  float r0 = 0.f, r1 = 0.f, r2 = 0.f, r3 = 0.f, runk = 0.f;
#define LC(i) (*reinterpret_cast<const u16x4*>(p + (size_t)(i) * 4096))
#define LK(i) (dok ? kp[(size_t)(i) * 64] : 0.f)
  u16x4 c0 = LC(0), c1 = LC(1), c2 = LC(2), c3 = LC(3);
  float k0 = LK(0), k1 = LK(1), k2 = LK(2), k3 = LK(3);
  for (int u = 0; u < 64; u += 4) {
    const int i4 = u + 4 < 64 ? u + 4 : 63, i5 = u + 5 < 64 ? u + 5 : 63;
    const int i6 = u + 6 < 64 ? u + 6 : 63, i7 = u + 7 < 64 ? u + 7 : 63;
    u16x4 n0 = LC(i4), n1 = LC(i5), n2 = LC(i6), n3 = LC(i7);
    float m0 = LK(i4), m1 = LK(i5), m2 = LK(i6), m3 = LK(i7);
#define STEP(idx, cv, kv)                                                  \
    {                                                                      \
      u16x4 o;                                                             \
      o.x = f2bf(r0); o.y = f2bf(r1); o.z = f2bf(r2); o.w = f2bf(r3);      \
      *reinterpret_cast<u16x4*>(p + (size_t)(idx) * 4096) = o;             \
      if (dok) kp[(size_t)(idx) * 64] = runk;                              \
      r0 += bf2f(cv.x); r1 += bf2f(cv.y); r2 += bf2f(cv.z);                \
      r3 += bf2f(cv.w); runk += kv;                                        \
    }
    STEP(u, c0, k0) STEP(u + 1, c1, k1) STEP(u + 2, c2, k2) STEP(u + 3, c3, k3)
#undef STEP
    c0 = n0; c1 = n1; c2 = n2; c3 = n3;
    k0 = m0; k1 = m1; k2 = m2; k3 = m3;
  }
#undef LC
#undef LK
}

// ---------------- apply: attn = (q @ ctx_excl) * Dinv -> AT -----------------
__global__ __launch_bounds__(256) void apply(
    const u16* __restrict__ Q, const u16* __restrict__ ctxc,
    const float* __restrict__ kcum, u16* __restrict__ AT) {
  const int bid = blockIdx.x;
  const int u = bid & 63, bh = bid >> 6, b = bh >> 4, h = bh & 15;
  const int tid = threadIdx.x, lane = tid & 63, wave = tid >> 6;
  const int l15 = lane & 15, l4 = lane >> 4;
  __shared__ float kc[64];
  __shared__ float dp[64][4];
  __shared__ float dinv[64];

  const size_t base = (size_t)bid * 4096;
  const u16* Qu = Q + base;
  if (tid < 64) kc[tid] = kcum[(size_t)bid * 64 + tid];
  __syncthreads();
  {
    int n = tid & 63, q = tid >> 6;
    const u16* qp = Qu + n * 64 + q * 16;
    float a = 0.f;
#pragma unroll
    for (int j = 0; j < 16; ++j) a += bf2f(qp[j]) * kc[q * 16 + j];
    dp[n][q] = a;
  }
  __syncthreads();
  if (tid < 64)
    dinv[tid] = 1.f / fmaxf(dp[tid][0] + dp[tid][1] + dp[tid][2] + dp[tid][3], 1e-3f);
  __syncthreads();

  f32x4 acc[4] = {};
  const u16* Cu = ctxc + base;
#pragma unroll
  for (int kk = 0; kk < 2; ++kk) {
    bf16x8 aq = *reinterpret_cast<const bf16x8*>(Qu + (wave * 16 + l15) * 64 + kk * 32 + l4 * 8);
#pragma unroll
    for (int ni = 0; ni < 4; ++ni) {
      bf16x8 bc = *reinterpret_cast<const bf16x8*>(Cu + (ni * 16 + l15) * 64 + kk * 32 + l4 * 8);
      acc[ni] = __builtin_amdgcn_mfma_f32_16x16x32_bf16(aq, bc, acc[ni], 0, 0, 0);
    }
  }
  const size_t orow = ((size_t)b * 4096 + u * 64 + wave * 16 + l4 * 4) * 1024 + h * 64;
#pragma unroll
  for (int i = 0; i < 4; ++i) {
    float di = dinv[wave * 16 + l4 * 4 + i];
#pragma unroll
    for (int ni = 0; ni < 4; ++ni)
      AT[orow + (size_t)i * 1024 + ni * 16 + l15] = f2bf(acc[ni][i] * di);
  }
}

// ----------------------------------------------------------------------------
extern "C" void kernel_launch(void* const* d_in, const int* in_sizes, int n_in,
                              void* d_out, int out_size, void* d_ws, size_t ws_size,
                              hipStream_t stream) {
  (void)in_sizes; (void)n_in; (void)out_size; (void)ws_size;
  const float* x      = (const float*)d_in[0];
  const float* qkv_w  = (const float*)d_in[1];
  const float* proj_w = (const float*)d_in[2];
  const float* proj_b = (const float*)d_in[3];
  float* out = (float*)d_out;

  char* ws = (char*)d_ws;
  u16* xb    = (u16*)(ws);
  u16* wq    = (u16*)(ws + 33554432);
  u16* wp    = (u16*)(ws + 39845888);
  u16* Qf    = (u16*)(ws + 41943040);
  u16* Kt    = (u16*)(ws + 75497472);
  u16* Vt    = (u16*)(ws + 109051904);
  u16* ctxb  = (u16*)(ws + 142606336);
  float* ksum = (float*)(ws + 176160768);
  u16* AT    = Kt;  // Kt is dead after buildctx; apply writes AT over it

  cvt_all<<<dim3(20480), dim3(256), 0, stream>>>(x, qkv_w, proj_w, xb, wq, wp);

  gemm256<2><<<dim3(64 * 12), dim3(512), 0, stream>>>(
      xb, wq, nullptr, nullptr, Qf, Kt, Vt, 3072, 1024, 16);
  buildctx<<<dim3(4096), dim3(256), 0, stream>>>(Kt, Vt, ctxb, ksum);
  scanctx<<<dim3(256), dim3(256), 0, stream>>>(ctxb, ksum);
  apply<<<dim3(4096), dim3(256), 0, stream>>>(Qf, ctxb, ksum, AT);
  gemm256<0><<<dim3(64 * 4), dim3(512), 0, stream>>>(
      AT, wp, proj_b, out, nullptr, nullptr, nullptr, 1024, 1024, 16);
}

// Round 10
// 240.599 us; speedup vs baseline: 1.1379x; 1.0354x over previous
//
#include <hip/hip_runtime.h>
#include <stdint.h>

// ---------------------------------------------------------------------------
// Bucketed linear attention, round 9:
//   - scanctx2: per-bucket K^TV fused WITH the exclusive scan — the MFMA
//     accumulator IS the running cumsum (fp32-exact). Blocks = bh x 4
//     e-chunks; K/V staged coalesced into padded LDS, double-buffered,
//     loads-early/ds_write-late. Replaces buildctx + ctx part of scanctx.
//   - ksum computed in gemm<2> K-epilogue (f32 exp in regs, wave holds 2
//     buckets x 64 d); tiny scanK does the 1MB exclusive scan.
//   ws layout (~177 MB):
//     xb   bf16 x             33,554,432 B @ 0
//     wq   bf16 qkv_w          6,291,456 B @ 33554432
//     wp   bf16 proj_w         2,097,152 B @ 39845888
//     Qf   bf16 [bkt][n][e]   33,554,432 B @ 41943040
//     Kt   bf16 [bkt][d][n]   33,554,432 B @ 75497472   (exp'd; AT reuses)
//     Vt   bf16 [bkt][e][n]   33,554,432 B @ 109051904
//     ctxb bf16 [bkt][e][d]   33,554,432 B @ 142606336  (excl-scanned)
//     ksum f32  [bkt][d]       1,048,576 B @ 176160768  (in-place excl scan)
// ---------------------------------------------------------------------------

typedef unsigned short u16;
typedef unsigned int u32;
typedef u16   u16x4  __attribute__((ext_vector_type(4)));
typedef u16   u16x8  __attribute__((ext_vector_type(8)));
typedef float f32x4  __attribute__((ext_vector_type(4)));
typedef float float4v __attribute__((ext_vector_type(4)));
typedef __bf16 bf16x8 __attribute__((ext_vector_type(8)));

__device__ __forceinline__ u16 f2bf(float f) {
  return __builtin_bit_cast(u16, (__bf16)f);
}
__device__ __forceinline__ float bf2f(u16 h) {
  return (float)__builtin_bit_cast(__bf16, h);
}

__device__ __forceinline__ void stage16(const u16* g, u16* l) {
  __builtin_amdgcn_global_load_lds(
      (const __attribute__((address_space(1))) u32*)g,
      (__attribute__((address_space(3))) u32*)l, 16, 0, 0);
}

// ------------------- fp32 -> bf16 convert (all 3 inputs) --------------------
__global__ __launch_bounds__(256) void cvt_all(
    const float* __restrict__ x, const float* __restrict__ wqf,
    const float* __restrict__ wpf, u16* __restrict__ xb,
    u16* __restrict__ wq, u16* __restrict__ wp) {
  int i = blockIdx.x * 256 + threadIdx.x;
  const float* in; u16* out; int j;
  if (i < 4194304)      { in = x;   out = xb; j = i; }
  else if (i < 4980736) { in = wqf; out = wq; j = i - 4194304; }
  else                  { in = wpf; out = wp; j = i - 4980736; }
  float4v v = reinterpret_cast<const float4v*>(in)[j];
  u16x4 o;
  o.x = f2bf(v.x); o.y = f2bf(v.y); o.z = f2bf(v.z); o.w = f2bf(v.w);
  reinterpret_cast<u16x4*>(out)[j] = o;
}

// ------------------ 256x256 NT bf16 MFMA GEMM (R3 schedule) -----------------
// EPI=0: float C + bias (proj). EPI=2: fused feature maps ->
//   bn 0-3: softmax_e(q)*e^-0.5 -> Qf[bkt][n][e]
//   bn 4-7: exp(k) -> Kt[bkt][d][n] (u16x4) + ksum[bkt][d] (f32 partials)
//   bn 8-11: v     -> Vt[bkt][e][n] (u16x4)
template <int EPI>
__global__ __launch_bounds__(512, 2) void gemm256(
    const u16* __restrict__ A,      // [M][K] bf16
    const u16* __restrict__ B,      // [N][K] bf16
    const float* __restrict__ bias, // [N] (EPI==0)
    float* __restrict__ Cf,         // (EPI==0)
    u16* __restrict__ Qf, u16* __restrict__ Kt, u16* __restrict__ Vt,
    float* __restrict__ ksum,
    int N, int K, int NT) {         // NT = K/64
  __shared__ u16 As[2][2][256][32];
  __shared__ u16 Bs[2][2][256][32];
  const int tid = threadIdx.x, lane = tid & 63, wave = tid >> 6;
  const int wm = wave >> 2, wn = wave & 3;
  const int l15 = lane & 15, l4 = lane >> 4;
  const int ntn = N >> 8;
  const int cpx = gridDim.x >> 3;
  const int bid = (blockIdx.x & 7) * cpx + (blockIdx.x >> 3);
  const int bm = bid / ntn, bn = bid % ntn;

  const int srow = tid >> 2;
  const int gsl8 = ((tid & 3) ^ ((tid >> 3) & 3)) * 8;
  const u16* Ag = A + (size_t)(bm * 256 + srow) * K + gsl8;
  const u16* Bg = B + (size_t)(bn * 256 + srow) * K + gsl8;
  const size_t rj = (size_t)128 * K;
  const int slotr = (l4 ^ ((l15 >> 1) & 3)) * 8;

  f32x4 acc[8][4] = {};
  bf16x8 a0, a1, a2, a3, a4, a5, a6, a7, b0, b1, b2, b3;

#define STG(P, buf, kh, kt)                                        \
  { const u16* g_ = P##g + (kt) + (kh) * 32;                       \
    stage16(g_,      &P##s[buf][kh][wave * 16][0]);                \
    stage16(g_ + rj, &P##s[buf][kh][128 + wave * 16][0]); }

#define LDA(r0_, r1_, r2_, r3_, kk, mh)                                  \
  { const u16* p_ = &As[cur][kk][wm * 128 + (mh) * 64 + l15][0] + slotr; \
    r0_ = *(const bf16x8*)(p_);                                          \
    r1_ = *(const bf16x8*)(p_ + 512);                                    \
    r2_ = *(const bf16x8*)(p_ + 1024);                                   \
    r3_ = *(const bf16x8*)(p_ + 1536); }

#define LDB(kk)                                                    \
  { const u16* p_ = &Bs[cur][kk][wn * 64 + l15][0] + slotr;        \
    b0 = *(const bf16x8*)(p_);                                     \
    b1 = *(const bf16x8*)(p_ + 512);                               \
    b2 = *(const bf16x8*)(p_ + 1024);                              \
    b3 = *(const bf16x8*)(p_ + 1536); }

#define MM(x, y, z) z = __builtin_amdgcn_mfma_f32_16x16x32_bf16(x, y, z, 0, 0, 0)
#define MFMA16(mb, x0, x1, x2, x3)                                 \
  __builtin_amdgcn_s_setprio(1);                                   \
  MM(x0, b0, acc[(mb) + 0][0]); MM(x0, b1, acc[(mb) + 0][1]);      \
  MM(x0, b2, acc[(mb) + 0][2]); MM(x0, b3, acc[(mb) + 0][3]);      \
  MM(x1, b0, acc[(mb) + 1][0]); MM(x1, b1, acc[(mb) + 1][1]);      \
  MM(x1, b2, acc[(mb) + 1][2]); MM(x1, b3, acc[(mb) + 1][3]);      \
  MM(x2, b0, acc[(mb) + 2][0]); MM(x2, b1, acc[(mb) + 2][1]);      \
  MM(x2, b2, acc[(mb) + 2][2]); MM(x2, b3, acc[(mb) + 2][3]);      \
  MM(x3, b0, acc[(mb) + 3][0]); MM(x3, b1, acc[(mb) + 3][1]);      \
  MM(x3, b2, acc[(mb) + 3][2]); MM(x3, b3, acc[(mb) + 3][3]);      \
  __builtin_amdgcn_s_setprio(0);

#define BARF()                                                     \
  { asm volatile("" ::: "memory");                                 \
    __builtin_amdgcn_s_barrier();                                  \
    asm volatile("" ::: "memory"); }

  STG(A, 0, 0, 0) STG(B, 0, 0, 0) STG(A, 0, 1, 0) STG(B, 0, 1, 0)
  asm volatile("s_waitcnt vmcnt(0)" ::: "memory");
  __builtin_amdgcn_s_barrier();
  asm volatile("" ::: "memory");

  for (int t = 0; t < NT; ++t) {
    const int cur = t & 1, nxt = cur ^ 1;
    const int ktn = (t + 1) << 6;
    const bool pre = (t + 1 < NT);
    LDB(0)
    LDA(a0, a1, a2, a3, 0, 0)
    LDA(a4, a5, a6, a7, 0, 1)
    if (pre) STG(A, nxt, 0, ktn)
    MFMA16(0, a0, a1, a2, a3)
    if (pre) STG(B, nxt, 0, ktn)
    MFMA16(4, a4, a5, a6, a7)
    if (pre) { asm volatile("s_waitcnt vmcnt(4)" ::: "memory"); }
    else     { asm volatile("s_waitcnt vmcnt(0)" ::: "memory"); }
    BARF()
    LDB(1)
    LDA(a0, a1, a2, a3, 1, 0)
    LDA(a4, a5, a6, a7, 1, 1)
    if (pre) STG(A, nxt, 1, ktn)
    MFMA16(0, a0, a1, a2, a3)
    if (pre) STG(B, nxt, 1, ktn)
    MFMA16(4, a4, a5, a6, a7)
    if (pre) { asm volatile("s_waitcnt vmcnt(4)" ::: "memory"); }
    BARF()
  }
#undef STG
#undef LDA
#undef LDB
#undef MM
#undef MFMA16
#undef BARF

  // epilogue: D row=(lane>>4)*4+reg, col=lane&15
  const int row0 = bm * 256 + wm * 128 + l4 * 4;
  const int col0 = bn * 256 + wn * 64 + l15;
  if constexpr (EPI == 0) {
    float bv[4];
#pragma unroll
    for (int ni = 0; ni < 4; ++ni) bv[ni] = bias[col0 + ni * 16];
#pragma unroll
    for (int mi = 0; mi < 8; ++mi)
#pragma unroll
      for (int i = 0; i < 4; ++i) {
        size_t r = (size_t)(row0 + mi * 16 + i) * N;
#pragma unroll
        for (int ni = 0; ni < 4; ++ni)
          Cf[r + col0 + ni * 16] = acc[mi][ni][i] + bv[ni];
      }
  } else {
    const int i3 = bn >> 2;                  // 0=q, 1=k, 2=v
    const int h  = ((bn & 3) << 2) + wn;     // global head 0..15
    if (i3 == 0) {
#pragma unroll
      for (int mi = 0; mi < 8; ++mi)
#pragma unroll
        for (int i = 0; i < 4; ++i) {
          const int row = row0 + mi * 16 + i;
          const int bb = row >> 12, uu = (row >> 6) & 63, nn = row & 63;
          u16* op = Qf + ((size_t)((bb * 16 + h) * 64 + uu)) * 4096
                        + nn * 64 + l15;
          float v0 = acc[mi][0][i], v1 = acc[mi][1][i];
          float v2 = acc[mi][2][i], v3 = acc[mi][3][i];
          float mx = fmaxf(fmaxf(v0, v1), fmaxf(v2, v3));
          mx = fmaxf(mx, __shfl_xor(mx, 1));
          mx = fmaxf(mx, __shfl_xor(mx, 2));
          mx = fmaxf(mx, __shfl_xor(mx, 4));
          mx = fmaxf(mx, __shfl_xor(mx, 8));
          float e0 = __expf(v0 - mx), e1 = __expf(v1 - mx);
          float e2 = __expf(v2 - mx), e3 = __expf(v3 - mx);
          float s = e0 + e1 + e2 + e3;
          s += __shfl_xor(s, 1); s += __shfl_xor(s, 2);
          s += __shfl_xor(s, 4); s += __shfl_xor(s, 8);
          float inv = 0.125f / s;  // e^-0.5 = 1/8
          op[0]  = f2bf(e0 * inv); op[16] = f2bf(e1 * inv);
          op[32] = f2bf(e2 * inv); op[48] = f2bf(e3 * inv);
        }
    } else if (i3 == 1) {
      // K: exp + transposed store + ksum partials (wave holds 2 buckets x 64d)
      float sk0[4] = {0.f, 0.f, 0.f, 0.f};
      float sk1[4] = {0.f, 0.f, 0.f, 0.f};
#pragma unroll
      for (int mi = 0; mi < 8; ++mi) {
        const int row = row0 + mi * 16;  // rows row..row+3 (same bucket)
        const int bb = row >> 12, uu = (row >> 6) & 63, nn = row & 63;
        u16* op = Kt + ((size_t)((bb * 16 + h) * 64 + uu)) * 4096 + nn;
#pragma unroll
        for (int ni = 0; ni < 4; ++ni) {
          float e0 = __expf(acc[mi][ni][0]);
          float e1 = __expf(acc[mi][ni][1]);
          float e2 = __expf(acc[mi][ni][2]);
          float e3 = __expf(acc[mi][ni][3]);
          u16x4 o;
          o.x = f2bf(e0); o.y = f2bf(e1); o.z = f2bf(e2); o.w = f2bf(e3);
          *reinterpret_cast<u16x4*>(op + (ni * 16 + l15) * 64) = o;
          if (mi < 4) sk0[ni] += e0 + e1 + e2 + e3;
          else        sk1[ni] += e0 + e1 + e2 + e3;
        }
      }
#pragma unroll
      for (int ni = 0; ni < 4; ++ni) {
        sk0[ni] += __shfl_xor(sk0[ni], 16); sk0[ni] += __shfl_xor(sk0[ni], 32);
        sk1[ni] += __shfl_xor(sk1[ni], 16); sk1[ni] += __shfl_xor(sk1[ni], 32);
      }
      if (lane < 16) {
        const int nb0 = bm * 256 + wm * 128;
        const size_t bkt0 = (size_t)(((nb0 >> 12) * 16 + h) * 64 + ((nb0 >> 6) & 63));
#pragma unroll
        for (int ni = 0; ni < 4; ++ni) {
          ksum[bkt0 * 64 + ni * 16 + l15]       = sk0[ni];
          ksum[(bkt0 + 1) * 64 + ni * 16 + l15] = sk1[ni];
        }
      }
    } else {
      // V: transposed store
#pragma unroll
      for (int mi = 0; mi < 8; ++mi) {
        const int row = row0 + mi * 16;
        const int bb = row >> 12, uu = (row >> 6) & 63, nn = row & 63;
        u16* op = Vt + ((size_t)((bb * 16 + h) * 64 + uu)) * 4096 + nn;
#pragma unroll
        for (int ni = 0; ni < 4; ++ni) {
          u16x4 o;
          o.x = f2bf(acc[mi][ni][0]); o.y = f2bf(acc[mi][ni][1]);
          o.z = f2bf(acc[mi][ni][2]); o.w = f2bf(acc[mi][ni][3]);
          *reinterpret_cast<u16x4*>(op + (ni * 16 + l15) * 64) = o;
        }
      }
    }
  }
}

// ------------- scanctx2: fused per-bucket K^TV + exclusive scan -------------
// Block = (bh, ec): 16 e-rows (ec*16..), all 64 d (4 waves x 16 d).
// MFMA accumulator IS the running fp32 cumsum: per bucket write acc
// (exclusive) then acc += V_frag . K_frag. K/V staged coalesced into padded
// LDS, double-buffered; global loads issued early, ds_write after compute.
__global__ __launch_bounds__(256) void scanctx2(
    const u16* __restrict__ Kt,  // [bkt][d][n] bf16 (exp'd)
    const u16* __restrict__ Vt,  // [bkt][e][n] bf16
    u16* __restrict__ ctxb) {    // [bkt][e][d] bf16 (excl-scanned out)
  const int bh = blockIdx.x >> 2, ec = blockIdx.x & 3;
  const int tid = threadIdx.x, lane = tid & 63, wave = tid >> 6;
  const int l15 = lane & 15, l4 = lane >> 4;
  __shared__ u16 KtL[2][64][72];
  __shared__ u16 VtL[2][16][72];

  const size_t bbase = (size_t)bh * 64 * 4096;
  // Kt chunks: c in [0,512): row=c>>3, slot=c&7 ; thread t -> c = t, t+256
  const int kr0 = tid >> 3, ks0 = (tid & 7) * 8;
  const int kr1 = 32 + kr0;
  // Vt chunks: t<128: row = ec*16 + (t>>3), slot t&7
  const bool dov = tid < 128;
  const int vr = tid >> 3, vs = (tid & 7) * 8;

  f32x4 acc = {0.f, 0.f, 0.f, 0.f};

  // prologue: load bucket 0 into buf 0
  u16x8 k0 = *reinterpret_cast<const u16x8*>(Kt + bbase + kr0 * 64 + ks0);
  u16x8 k1 = *reinterpret_cast<const u16x8*>(Kt + bbase + kr1 * 64 + ks0);
  u16x8 v0 = {};
  if (dov) v0 = *reinterpret_cast<const u16x8*>(Vt + bbase + (ec * 16 + vr) * 64 + vs);
  *reinterpret_cast<u16x8*>(&KtL[0][kr0][ks0]) = k0;
  *reinterpret_cast<u16x8*>(&KtL[0][kr1][ks0]) = k1;
  if (dov) *reinterpret_cast<u16x8*>(&VtL[0][vr][vs]) = v0;
  __syncthreads();

  for (int u = 0; u < 64; ++u) {
    const int cur = u & 1, nxt = cur ^ 1;
    const bool pre = (u + 1 < 64);
    // issue next bucket's global loads early (land under compute below)
    if (pre) {
      const size_t nb = bbase + (size_t)(u + 1) * 4096;
      k0 = *reinterpret_cast<const u16x8*>(Kt + nb + kr0 * 64 + ks0);
      k1 = *reinterpret_cast<const u16x8*>(Kt + nb + kr1 * 64 + ks0);
      if (dov) v0 = *reinterpret_cast<const u16x8*>(Vt + nb + (ec * 16 + vr) * 64 + vs);
    }
    // write exclusive prefix (acc = sum of buckets < u)
    {
      u16* cb = ctxb + (bbase + (size_t)u * 4096) + wave * 16 + l15;
#pragma unroll
      for (int i = 0; i < 4; ++i)
        cb[(ec * 16 + l4 * 4 + i) * 64] = f2bf(acc[i]);
    }
    // accumulate bucket u: acc += V[16e] . K[16d] over n=64
#pragma unroll
    for (int kk = 0; kk < 2; ++kk) {
      bf16x8 av = *reinterpret_cast<const bf16x8*>(&VtL[cur][l15][kk * 32 + l4 * 8]);
      bf16x8 bk = *reinterpret_cast<const bf16x8*>(&KtL[cur][wave * 16 + l15][kk * 32 + l4 * 8]);
      acc = __builtin_amdgcn_mfma_f32_16x16x32_bf16(av, bk, acc, 0, 0, 0);
    }
    // land next bucket into the other buffer
    if (pre) {
      *reinterpret_cast<u16x8*>(&KtL[nxt][kr0][ks0]) = k0;
      *reinterpret_cast<u16x8*>(&KtL[nxt][kr1][ks0]) = k1;
      if (dov) *reinterpret_cast<u16x8*>(&VtL[nxt][vr][vs]) = v0;
    }
    __syncthreads();
  }
}

// ---------------- scanK: in-place exclusive cumsum of ksum over u -----------
__global__ __launch_bounds__(64) void scanK(float* __restrict__ ksum) {
  const int bh = blockIdx.x;
  float* p = ksum + (size_t)bh * 4096 + threadIdx.x;
  float run = 0.f;
#define LK(i) p[(size_t)(i) * 64]
  float c0 = LK(0), c1 = LK(1), c2 = LK(2), c3 = LK(3);
  for (int u = 0; u < 64; u += 4) {
    const int i4 = u + 4 < 64 ? u + 4 : 63, i5 = u + 5 < 64 ? u + 5 : 63;
    const int i6 = u + 6 < 64 ? u + 6 : 63, i7 = u + 7 < 64 ? u + 7 : 63;
    float n0 = LK(i4), n1 = LK(i5), n2 = LK(i6), n3 = LK(i7);
    LK(u) = run;     run += c0;
    LK(u + 1) = run; run += c1;
    LK(u + 2) = run; run += c2;
    LK(u + 3) = run; run += c3;
    c0 = n0; c1 = n1; c2 = n2; c3 = n3;
  }
#undef LK
}

// ---------------- apply: attn = (q @ ctx_excl) * Dinv -> AT -----------------
__global__ __launch_bounds__(256) void apply(
    const u16* __restrict__ Q, const u16* __restrict__ ctxc,
    const float* __restrict__ kcum, u16* __restrict__ AT) {
  const int bid = blockIdx.x;
  const int u = bid & 63, bh = bid >> 6, b = bh >> 4, h = bh & 15;
  const int tid = threadIdx.x, lane = tid & 63, wave = tid >> 6;
  const int l15 = lane & 15, l4 = lane >> 4;
  __shared__ float kc[64];
  __shared__ float dp[64][4];
  __shared__ float dinv[64];

  const size_t base = (size_t)bid * 4096;
  const u16* Qu = Q + base;
  if (tid < 64) kc[tid] = kcum[(size_t)bid * 64 + tid];
  __syncthreads();
  {
    int n = tid & 63, q = tid >> 6;
    const u16* qp = Qu + n * 64 + q * 16;
    float a = 0.f;
#pragma unroll
    for (int j = 0; j < 16; ++j) a += bf2f(qp[j]) * kc[q * 16 + j];
    dp[n][q] = a;
  }
  __syncthreads();
  if (tid < 64)
    dinv[tid] = 1.f / fmaxf(dp[tid][0] + dp[tid][1] + dp[tid][2] + dp[tid][3], 1e-3f);
  __syncthreads();

  f32x4 acc[4] = {};
  const u16* Cu = ctxc + base;
#pragma unroll
  for (int kk = 0; kk < 2; ++kk) {
    bf16x8 aq = *reinterpret_cast<const bf16x8*>(Qu + (wave * 16 + l15) * 64 + kk * 32 + l4 * 8);
#pragma unroll
    for (int ni = 0; ni < 4; ++ni) {
      bf16x8 bc = *reinterpret_cast<const bf16x8*>(Cu + (ni * 16 + l15) * 64 + kk * 32 + l4 * 8);
      acc[ni] = __builtin_amdgcn_mfma_f32_16x16x32_bf16(aq, bc, acc[ni], 0, 0, 0);
    }
  }
  const size_t orow = ((size_t)b * 4096 + u * 64 + wave * 16 + l4 * 4) * 1024 + h * 64;
#pragma unroll
  for (int i = 0; i < 4; ++i) {
    float di = dinv[wave * 16 + l4 * 4 + i];
#pragma unroll
    for (int ni = 0; ni < 4; ++ni)
      AT[orow + (size_t)i * 1024 + ni * 16 + l15] = f2bf(acc[ni][i] * di);
  }
}

// ----------------------------------------------------------------------------
extern "C" void kernel_launch(void* const* d_in, const int* in_sizes, int n_in,
                              void* d_out, int out_size, void* d_ws, size_t ws_size,
                              hipStream_t stream) {
  (void)in_sizes; (void)n_in; (void)out_size; (void)ws_size;
  const float* x      = (const float*)d_in[0];
  const float* qkv_w  = (const float*)d_in[1];
  const float* proj_w = (const float*)d_in[2];
  const float* proj_b = (const float*)d_in[3];
  float* out = (float*)d_out;

  char* ws = (char*)d_ws;
  u16* xb    = (u16*)(ws);
  u16* wq    = (u16*)(ws + 33554432);
  u16* wp    = (u16*)(ws + 39845888);
  u16* Qf    = (u16*)(ws + 41943040);
  u16* Kt    = (u16*)(ws + 75497472);
  u16* Vt    = (u16*)(ws + 109051904);
  u16* ctxb  = (u16*)(ws + 142606336);
  float* ksum = (float*)(ws + 176160768);
  u16* AT    = Kt;  // Kt is dead after scanctx2; apply writes AT over it

  cvt_all<<<dim3(20480), dim3(256), 0, stream>>>(x, qkv_w, proj_w, xb, wq, wp);

  gemm256<2><<<dim3(64 * 12), dim3(512), 0, stream>>>(
      xb, wq, nullptr, nullptr, Qf, Kt, Vt, ksum, 3072, 1024, 16);
  scanK<<<dim3(64), dim3(64), 0, stream>>>(ksum);
  scanctx2<<<dim3(256), dim3(256), 0, stream>>>(Kt, Vt, ctxb);
  apply<<<dim3(4096), dim3(256), 0, stream>>>(Qf, ctxb, ksum, AT);
  gemm256<0><<<dim3(64 * 4), dim3(512), 0, stream>>>(
      AT, wp, proj_b, out, nullptr, nullptr, nullptr, nullptr, 1024, 1024, 16);
}

// Round 11
// 234.253 us; speedup vs baseline: 1.1688x; 1.0271x over previous
//
#include <hip/hip_runtime.h>
#include <stdint.h>

// ---------------------------------------------------------------------------
// Bucketed linear attention, round 10: R9 +
//   - scanctx2 v2: 2 buckets per barrier-iteration (32 serial iters, loads
//     one iteration ahead) — latency-bound loop halved.
//   - apply v2: D-dot fused into the MFMA fragment loads (shfl reduce over
//     l4, shfl redistribute) — removes scalar Qf re-read + 2 barriers.
//   ws layout (~177 MB):
//     xb   bf16 x             33,554,432 B @ 0
//     wq   bf16 qkv_w          6,291,456 B @ 33554432
//     wp   bf16 proj_w         2,097,152 B @ 39845888
//     Qf   bf16 [bkt][n][e]   33,554,432 B @ 41943040
//     Kt   bf16 [bkt][d][n]   33,554,432 B @ 75497472   (exp'd; AT reuses)
//     Vt   bf16 [bkt][e][n]   33,554,432 B @ 109051904
//     ctxb bf16 [bkt][e][d]   33,554,432 B @ 142606336  (excl-scanned)
//     ksum f32  [bkt][d]       1,048,576 B @ 176160768  (in-place excl scan)
// ---------------------------------------------------------------------------

typedef unsigned short u16;
typedef unsigned int u32;
typedef u16   u16x4  __attribute__((ext_vector_type(4)));
typedef u16   u16x8  __attribute__((ext_vector_type(8)));
typedef float f32x4  __attribute__((ext_vector_type(4)));
typedef float float4v __attribute__((ext_vector_type(4)));
typedef __bf16 bf16x8 __attribute__((ext_vector_type(8)));

__device__ __forceinline__ u16 f2bf(float f) {
  return __builtin_bit_cast(u16, (__bf16)f);
}
__device__ __forceinline__ float bf2f(u16 h) {
  return (float)__builtin_bit_cast(__bf16, h);
}

__device__ __forceinline__ void stage16(const u16* g, u16* l) {
  __builtin_amdgcn_global_load_lds(
      (const __attribute__((address_space(1))) u32*)g,
      (__attribute__((address_space(3))) u32*)l, 16, 0, 0);
}

// ------------------- fp32 -> bf16 convert (all 3 inputs) --------------------
__global__ __launch_bounds__(256) void cvt_all(
    const float* __restrict__ x, const float* __restrict__ wqf,
    const float* __restrict__ wpf, u16* __restrict__ xb,
    u16* __restrict__ wq, u16* __restrict__ wp) {
  int i = blockIdx.x * 256 + threadIdx.x;
  const float* in; u16* out; int j;
  if (i < 4194304)      { in = x;   out = xb; j = i; }
  else if (i < 4980736) { in = wqf; out = wq; j = i - 4194304; }
  else                  { in = wpf; out = wp; j = i - 4980736; }
  float4v v = reinterpret_cast<const float4v*>(in)[j];
  u16x4 o;
  o.x = f2bf(v.x); o.y = f2bf(v.y); o.z = f2bf(v.z); o.w = f2bf(v.w);
  reinterpret_cast<u16x4*>(out)[j] = o;
}

// ------------------ 256x256 NT bf16 MFMA GEMM (R3 schedule) -----------------
// EPI=0: float C + bias (proj). EPI=2: fused feature maps ->
//   bn 0-3: softmax_e(q)*e^-0.5 -> Qf[bkt][n][e]
//   bn 4-7: exp(k) -> Kt[bkt][d][n] (u16x4) + ksum[bkt][d] (f32 partials)
//   bn 8-11: v     -> Vt[bkt][e][n] (u16x4)
template <int EPI>
__global__ __launch_bounds__(512, 2) void gemm256(
    const u16* __restrict__ A,      // [M][K] bf16
    const u16* __restrict__ B,      // [N][K] bf16
    const float* __restrict__ bias, // [N] (EPI==0)
    float* __restrict__ Cf,         // (EPI==0)
    u16* __restrict__ Qf, u16* __restrict__ Kt, u16* __restrict__ Vt,
    float* __restrict__ ksum,
    int N, int K, int NT) {         // NT = K/64
  __shared__ u16 As[2][2][256][32];
  __shared__ u16 Bs[2][2][256][32];
  const int tid = threadIdx.x, lane = tid & 63, wave = tid >> 6;
  const int wm = wave >> 2, wn = wave & 3;
  const int l15 = lane & 15, l4 = lane >> 4;
  const int ntn = N >> 8;
  const int cpx = gridDim.x >> 3;
  const int bid = (blockIdx.x & 7) * cpx + (blockIdx.x >> 3);
  const int bm = bid / ntn, bn = bid % ntn;

  const int srow = tid >> 2;
  const int gsl8 = ((tid & 3) ^ ((tid >> 3) & 3)) * 8;
  const u16* Ag = A + (size_t)(bm * 256 + srow) * K + gsl8;
  const u16* Bg = B + (size_t)(bn * 256 + srow) * K + gsl8;
  const size_t rj = (size_t)128 * K;
  const int slotr = (l4 ^ ((l15 >> 1) & 3)) * 8;

  f32x4 acc[8][4] = {};
  bf16x8 a0, a1, a2, a3, a4, a5, a6, a7, b0, b1, b2, b3;

#define STG(P, buf, kh, kt)                                        \
  { const u16* g_ = P##g + (kt) + (kh) * 32;                       \
    stage16(g_,      &P##s[buf][kh][wave * 16][0]);                \
    stage16(g_ + rj, &P##s[buf][kh][128 + wave * 16][0]); }

#define LDA(r0_, r1_, r2_, r3_, kk, mh)                                  \
  { const u16* p_ = &As[cur][kk][wm * 128 + (mh) * 64 + l15][0] + slotr; \
    r0_ = *(const bf16x8*)(p_);                                          \
    r1_ = *(const bf16x8*)(p_ + 512);                                    \
    r2_ = *(const bf16x8*)(p_ + 1024);                                   \
    r3_ = *(const bf16x8*)(p_ + 1536); }

#define LDB(kk)                                                    \
  { const u16* p_ = &Bs[cur][kk][wn * 64 + l15][0] + slotr;        \
    b0 = *(const bf16x8*)(p_);                                     \
    b1 = *(const bf16x8*)(p_ + 512);                               \
    b2 = *(const bf16x8*)(p_ + 1024);                              \
    b3 = *(const bf16x8*)(p_ + 1536); }

#define MM(x, y, z) z = __builtin_amdgcn_mfma_f32_16x16x32_bf16(x, y, z, 0, 0, 0)
#define MFMA16(mb, x0, x1, x2, x3)                                 \
  __builtin_amdgcn_s_setprio(1);                                   \
  MM(x0, b0, acc[(mb) + 0][0]); MM(x0, b1, acc[(mb) + 0][1]);      \
  MM(x0, b2, acc[(mb) + 0][2]); MM(x0, b3, acc[(mb) + 0][3]);      \
  MM(x1, b0, acc[(mb) + 1][0]); MM(x1, b1, acc[(mb) + 1][1]);      \
  MM(x1, b2, acc[(mb) + 1][2]); MM(x1, b3, acc[(mb) + 1][3]);      \
  MM(x2, b0, acc[(mb) + 2][0]); MM(x2, b1, acc[(mb) + 2][1]);      \
  MM(x2, b2, acc[(mb) + 2][2]); MM(x2, b3, acc[(mb) + 2][3]);      \
  MM(x3, b0, acc[(mb) + 3][0]); MM(x3, b1, acc[(mb) + 3][1]);      \
  MM(x3, b2, acc[(mb) + 3][2]); MM(x3, b3, acc[(mb) + 3][3]);      \
  __builtin_amdgcn_s_setprio(0);

#define BARF()                                                     \
  { asm volatile("" ::: "memory");                                 \
    __builtin_amdgcn_s_barrier();                                  \
    asm volatile("" ::: "memory"); }

  STG(A, 0, 0, 0) STG(B, 0, 0, 0) STG(A, 0, 1, 0) STG(B, 0, 1, 0)
  asm volatile("s_waitcnt vmcnt(0)" ::: "memory");
  __builtin_amdgcn_s_barrier();
  asm volatile("" ::: "memory");

  for (int t = 0; t < NT; ++t) {
    const int cur = t & 1, nxt = cur ^ 1;
    const int ktn = (t + 1) << 6;
    const bool pre = (t + 1 < NT);
    LDB(0)
    LDA(a0, a1, a2, a3, 0, 0)
    LDA(a4, a5, a6, a7, 0, 1)
    if (pre) STG(A, nxt, 0, ktn)
    MFMA16(0, a0, a1, a2, a3)
    if (pre) STG(B, nxt, 0, ktn)
    MFMA16(4, a4, a5, a6, a7)
    if (pre) { asm volatile("s_waitcnt vmcnt(4)" ::: "memory"); }
    else     { asm volatile("s_waitcnt vmcnt(0)" ::: "memory"); }
    BARF()
    LDB(1)
    LDA(a0, a1, a2, a3, 1, 0)
    LDA(a4, a5, a6, a7, 1, 1)
    if (pre) STG(A, nxt, 1, ktn)
    MFMA16(0, a0, a1, a2, a3)
    if (pre) STG(B, nxt, 1, ktn)
    MFMA16(4, a4, a5, a6, a7)
    if (pre) { asm volatile("s_waitcnt vmcnt(4)" ::: "memory"); }
    BARF()
  }
#undef STG
#undef LDA
#undef LDB
#undef MM
#undef MFMA16
#undef BARF

  // epilogue: D row=(lane>>4)*4+reg, col=lane&15
  const int row0 = bm * 256 + wm * 128 + l4 * 4;
  const int col0 = bn * 256 + wn * 64 + l15;
  if constexpr (EPI == 0) {
    float bv[4];
#pragma unroll
    for (int ni = 0; ni < 4; ++ni) bv[ni] = bias[col0 + ni * 16];
#pragma unroll
    for (int mi = 0; mi < 8; ++mi)
#pragma unroll
      for (int i = 0; i < 4; ++i) {
        size_t r = (size_t)(row0 + mi * 16 + i) * N;
#pragma unroll
        for (int ni = 0; ni < 4; ++ni)
          Cf[r + col0 + ni * 16] = acc[mi][ni][i] + bv[ni];
      }
  } else {
    const int i3 = bn >> 2;                  // 0=q, 1=k, 2=v
    const int h  = ((bn & 3) << 2) + wn;     // global head 0..15
    if (i3 == 0) {
#pragma unroll
      for (int mi = 0; mi < 8; ++mi)
#pragma unroll
        for (int i = 0; i < 4; ++i) {
          const int row = row0 + mi * 16 + i;
          const int bb = row >> 12, uu = (row >> 6) & 63, nn = row & 63;
          u16* op = Qf + ((size_t)((bb * 16 + h) * 64 + uu)) * 4096
                        + nn * 64 + l15;
          float v0 = acc[mi][0][i], v1 = acc[mi][1][i];
          float v2 = acc[mi][2][i], v3 = acc[mi][3][i];
          float mx = fmaxf(fmaxf(v0, v1), fmaxf(v2, v3));
          mx = fmaxf(mx, __shfl_xor(mx, 1));
          mx = fmaxf(mx, __shfl_xor(mx, 2));
          mx = fmaxf(mx, __shfl_xor(mx, 4));
          mx = fmaxf(mx, __shfl_xor(mx, 8));
          float e0 = __expf(v0 - mx), e1 = __expf(v1 - mx);
          float e2 = __expf(v2 - mx), e3 = __expf(v3 - mx);
          float s = e0 + e1 + e2 + e3;
          s += __shfl_xor(s, 1); s += __shfl_xor(s, 2);
          s += __shfl_xor(s, 4); s += __shfl_xor(s, 8);
          float inv = 0.125f / s;  // e^-0.5 = 1/8
          op[0]  = f2bf(e0 * inv); op[16] = f2bf(e1 * inv);
          op[32] = f2bf(e2 * inv); op[48] = f2bf(e3 * inv);
        }
    } else if (i3 == 1) {
      // K: exp + transposed store + ksum partials (wave holds 2 buckets x 64d)
      float sk0[4] = {0.f, 0.f, 0.f, 0.f};
      float sk1[4] = {0.f, 0.f, 0.f, 0.f};
#pragma unroll
      for (int mi = 0; mi < 8; ++mi) {
        const int row = row0 + mi * 16;  // rows row..row+3 (same bucket)
        const int bb = row >> 12, uu = (row >> 6) & 63, nn = row & 63;
        u16* op = Kt + ((size_t)((bb * 16 + h) * 64 + uu)) * 4096 + nn;
#pragma unroll
        for (int ni = 0; ni < 4; ++ni) {
          float e0 = __expf(acc[mi][ni][0]);
          float e1 = __expf(acc[mi][ni][1]);
          float e2 = __expf(acc[mi][ni][2]);
          float e3 = __expf(acc[mi][ni][3]);
          u16x4 o;
          o.x = f2bf(e0); o.y = f2bf(e1); o.z = f2bf(e2); o.w = f2bf(e3);
          *reinterpret_cast<u16x4*>(op + (ni * 16 + l15) * 64) = o;
          if (mi < 4) sk0[ni] += e0 + e1 + e2 + e3;
          else        sk1[ni] += e0 + e1 + e2 + e3;
        }
      }
#pragma unroll
      for (int ni = 0; ni < 4; ++ni) {
        sk0[ni] += __shfl_xor(sk0[ni], 16); sk0[ni] += __shfl_xor(sk0[ni], 32);
        sk1[ni] += __shfl_xor(sk1[ni], 16); sk1[ni] += __shfl_xor(sk1[ni], 32);
      }
      if (lane < 16) {
        const int nb0 = bm * 256 + wm * 128;
        const size_t bkt0 = (size_t)(((nb0 >> 12) * 16 + h) * 64 + ((nb0 >> 6) & 63));
#pragma unroll
        for (int ni = 0; ni < 4; ++ni) {
          ksum[bkt0 * 64 + ni * 16 + l15]       = sk0[ni];
          ksum[(bkt0 + 1) * 64 + ni * 16 + l15] = sk1[ni];
        }
      }
    } else {
      // V: transposed store
#pragma unroll
      for (int mi = 0; mi < 8; ++mi) {
        const int row = row0 + mi * 16;
        const int bb = row >> 12, uu = (row >> 6) & 63, nn = row & 63;
        u16* op = Vt + ((size_t)((bb * 16 + h) * 64 + uu)) * 4096 + nn;
#pragma unroll
        for (int ni = 0; ni < 4; ++ni) {
          u16x4 o;
          o.x = f2bf(acc[mi][ni][0]); o.y = f2bf(acc[mi][ni][1]);
          o.z = f2bf(acc[mi][ni][2]); o.w = f2bf(acc[mi][ni][3]);
          *reinterpret_cast<u16x4*>(op + (ni * 16 + l15) * 64) = o;
        }
      }
    }
  }
}

// ------------- scanctx2 v2: fused K^TV + exclusive scan, 2 buckets/iter ----
// Block = (bh, ec): 16 e-rows, all 64 d. MFMA accumulator IS the running
// fp32 cumsum. 2 buckets per barrier-iteration (32 iters); global loads for
// the next pair issued at iteration start; ds_writes after compute.
__global__ __launch_bounds__(256) void scanctx2(
    const u16* __restrict__ Kt,  // [bkt][d][n] bf16 (exp'd)
    const u16* __restrict__ Vt,  // [bkt][e][n] bf16
    u16* __restrict__ ctxb) {    // [bkt][e][d] bf16 (excl-scanned out)
  const int bh = blockIdx.x >> 2, ec = blockIdx.x & 3;
  const int tid = threadIdx.x, lane = tid & 63, wave = tid >> 6;
  const int l15 = lane & 15, l4 = lane >> 4;
  __shared__ u16 KtL[2][2][64][72];  // [buf][bkt parity][d][n]
  __shared__ u16 VtL[2][2][16][72];

  const size_t bbase = (size_t)bh * 64 * 4096;
  const int kr0 = tid >> 3, ks = (tid & 7) * 8;
  const int kr1 = 32 + kr0;
  const bool dov = tid < 128;
  const int vr = tid >> 3, vs = (tid & 7) * 8;

  f32x4 acc = {0.f, 0.f, 0.f, 0.f};
  u16x8 ka0, ka1, kb0, kb1, va = {}, vb = {};

#define GLD(u_, kx0, kx1, vx)                                          \
  { const size_t nb = bbase + (size_t)(u_) * 4096;                     \
    kx0 = *reinterpret_cast<const u16x8*>(Kt + nb + kr0 * 64 + ks);    \
    kx1 = *reinterpret_cast<const u16x8*>(Kt + nb + kr1 * 64 + ks);    \
    if (dov) vx = *reinterpret_cast<const u16x8*>(                     \
        Vt + nb + (ec * 16 + vr) * 64 + vs); }
#define LWR(buf, j, kx0, kx1, vx)                                      \
  { *reinterpret_cast<u16x8*>(&KtL[buf][j][kr0][ks]) = kx0;            \
    *reinterpret_cast<u16x8*>(&KtL[buf][j][kr1][ks]) = kx1;            \
    if (dov) *reinterpret_cast<u16x8*>(&VtL[buf][j][vr][vs]) = vx; }
#define ACC(buf, j)                                                    \
  _Pragma("unroll")                                                    \
  for (int kk = 0; kk < 2; ++kk) {                                     \
    bf16x8 av = *reinterpret_cast<const bf16x8*>(                      \
        &VtL[buf][j][l15][kk * 32 + l4 * 8]);                          \
    bf16x8 bk = *reinterpret_cast<const bf16x8*>(                      \
        &KtL[buf][j][wave * 16 + l15][kk * 32 + l4 * 8]);              \
    acc = __builtin_amdgcn_mfma_f32_16x16x32_bf16(av, bk, acc, 0, 0, 0); }

  GLD(0, ka0, ka1, va) GLD(1, kb0, kb1, vb)
  LWR(0, 0, ka0, ka1, va) LWR(0, 1, kb0, kb1, vb)
  __syncthreads();

  for (int u = 0; u < 64; u += 2) {
    const int cur = (u >> 1) & 1, nxt = cur ^ 1;
    const bool pre = (u + 2 < 64);
    if (pre) { GLD(u + 2, ka0, ka1, va) GLD(u + 3, kb0, kb1, vb) }
    u16* cb0 = ctxb + bbase + (size_t)u * 4096 + wave * 16 + l15;
#pragma unroll
    for (int i = 0; i < 4; ++i) cb0[(ec * 16 + l4 * 4 + i) * 64] = f2bf(acc[i]);
    ACC(cur, 0)
    u16* cb1 = cb0 + 4096;
#pragma unroll
    for (int i = 0; i < 4; ++i) cb1[(ec * 16 + l4 * 4 + i) * 64] = f2bf(acc[i]);
    ACC(cur, 1)
    if (pre) { LWR(nxt, 0, ka0, ka1, va) LWR(nxt, 1, kb0, kb1, vb) }
    __syncthreads();
  }
#undef GLD
#undef LWR
#undef ACC
}

// ---------------- scanK: in-place exclusive cumsum of ksum over u -----------
__global__ __launch_bounds__(64) void scanK(float* __restrict__ ksum) {
  const int bh = blockIdx.x;
  float* p = ksum + (size_t)bh * 4096 + threadIdx.x;
  float run = 0.f;
#define LK(i) p[(size_t)(i) * 64]
  float c0 = LK(0), c1 = LK(1), c2 = LK(2), c3 = LK(3);
  for (int u = 0; u < 64; u += 4) {
    const int i4 = u + 4 < 64 ? u + 4 : 63, i5 = u + 5 < 64 ? u + 5 : 63;
    const int i6 = u + 6 < 64 ? u + 6 : 63, i7 = u + 7 < 64 ? u + 7 : 63;
    float n0 = LK(i4), n1 = LK(i5), n2 = LK(i6), n3 = LK(i7);
    LK(u) = run;     run += c0;
    LK(u + 1) = run; run += c1;
    LK(u + 2) = run; run += c2;
    LK(u + 3) = run; run += c3;
    c0 = n0; c1 = n1; c2 = n2; c3 = n3;
  }
#undef LK
}

// -------- apply v2: attn = (q @ ctx_excl) * Dinv -> AT (fused D-dot) --------
__global__ __launch_bounds__(256) void apply(
    const u16* __restrict__ Q, const u16* __restrict__ ctxc,
    const float* __restrict__ kcum, u16* __restrict__ AT) {
  const int bid = blockIdx.x;
  const int u = bid & 63, bh = bid >> 6, b = bh >> 4, h = bh & 15;
  const int tid = threadIdx.x, lane = tid & 63, wave = tid >> 6;
  const int l15 = lane & 15, l4 = lane >> 4;
  __shared__ float kc[64];

  const size_t base = (size_t)bid * 4096;
  if (tid < 64) kc[tid] = kcum[(size_t)bid * 64 + tid];
  __syncthreads();

  // q fragments + fused D partial: lane holds q[row=wave*16+l15][kk*32+l4*8..]
  bf16x8 aq[2];
  float dpart = 0.f;
#pragma unroll
  for (int kk = 0; kk < 2; ++kk) {
    aq[kk] = *reinterpret_cast<const bf16x8*>(
        Q + base + (wave * 16 + l15) * 64 + kk * 32 + l4 * 8);
    const float* kcp = &kc[kk * 32 + l4 * 8];
#pragma unroll
    for (int j = 0; j < 8; ++j) dpart += (float)aq[kk][j] * kcp[j];
  }
  dpart += __shfl_xor(dpart, 16);
  dpart += __shfl_xor(dpart, 32);
  const float dinv_self = 1.f / fmaxf(dpart, 1e-3f);  // D for row wave*16+l15
  float dv[4];
#pragma unroll
  for (int i = 0; i < 4; ++i) dv[i] = __shfl(dinv_self, l4 * 4 + i);

  f32x4 acc[4] = {};
  const u16* Cu = ctxc + base;
#pragma unroll
  for (int kk = 0; kk < 2; ++kk)
#pragma unroll
    for (int ni = 0; ni < 4; ++ni) {
      bf16x8 bc = *reinterpret_cast<const bf16x8*>(
          Cu + (ni * 16 + l15) * 64 + kk * 32 + l4 * 8);
      acc[ni] = __builtin_amdgcn_mfma_f32_16x16x32_bf16(aq[kk], bc, acc[ni], 0, 0, 0);
    }
  const size_t orow = ((size_t)b * 4096 + u * 64 + wave * 16 + l4 * 4) * 1024 + h * 64;
#pragma unroll
  for (int i = 0; i < 4; ++i) {
#pragma unroll
    for (int ni = 0; ni < 4; ++ni)
      AT[orow + (size_t)i * 1024 + ni * 16 + l15] = f2bf(acc[ni][i] * dv[i]);
  }
}

// ----------------------------------------------------------------------------
extern "C" void kernel_launch(void* const* d_in, const int* in_sizes, int n_in,
                              void* d_out, int out_size, void* d_ws, size_t ws_size,
                              hipStream_t stream) {
  (void)in_sizes; (void)n_in; (void)out_size; (void)ws_size;
  const float* x      = (const float*)d_in[0];
  const float* qkv_w  = (const float*)d_in[1];
  const float* proj_w = (const float*)d_in[2];
  const float* proj_b = (const float*)d_in[3];
  float* out = (float*)d_out;

  char* ws = (char*)d_ws;
  u16* xb    = (u16*)(ws);
  u16* wq    = (u16*)(ws + 33554432);
  u16* wp    = (u16*)(ws + 39845888);
  u16* Qf    = (u16*)(ws + 41943040);
  u16* Kt    = (u16*)(ws + 75497472);
  u16* Vt    = (u16*)(ws + 109051904);
  u16* ctxb  = (u16*)(ws + 142606336);
  float* ksum = (float*)(ws + 176160768);
  u16* AT    = Kt;  // Kt is dead after scanctx2; apply writes AT over it

  cvt_all<<<dim3(20480), dim3(256), 0, stream>>>(x, qkv_w, proj_w, xb, wq, wp);

  gemm256<2><<<dim3(64 * 12), dim3(512), 0, stream>>>(
      xb, wq, nullptr, nullptr, Qf, Kt, Vt, ksum, 3072, 1024, 16);
  scanK<<<dim3(64), dim3(64), 0, stream>>>(ksum);
  scanctx2<<<dim3(256), dim3(256), 0, stream>>>(Kt, Vt, ctxb);
  apply<<<dim3(4096), dim3(256), 0, stream>>>(Qf, ctxb, ksum, AT);
  gemm256<0><<<dim3(64 * 4), dim3(512), 0, stream>>>(
      AT, wp, proj_b, out, nullptr, nullptr, nullptr, nullptr, 1024, 1024, 16);
}